// Round 5
// baseline (11485.345 us; speedup 1.0000x reference)
//
#include <hip/hip_runtime.h>
#include <math.h>

#define Bc 16
#define Tc 2048
#define Dc 512
#define Hc 1024
#define Rc 16

// ---------------------------------------------------------------------------
// GEMM: out[M,1024] = X[M,512] @ W[512,1024], M = 32768.
// ---------------------------------------------------------------------------
__global__ __launch_bounds__(256) void gemm_xw(const float* __restrict__ X,
                                               const float* __restrict__ W,
                                               float* __restrict__ out)
{
    __shared__ float As[16][128];
    __shared__ float Bs[16][64];
    const int tid = threadIdx.x;
    const int m0 = blockIdx.x * 128;
    const int n0 = blockIdx.y * 64;
    const int tx = tid & 15, ty = tid >> 4;
    const int am = tid >> 2, ak = (tid & 3) * 4;
    const int bk = tid >> 4, bn = (tid & 15) * 4;
    float acc[8][4] = {};
    for (int k0 = 0; k0 < 512; k0 += 16) {
        if (k0) __syncthreads();
        float4 a0 = *(const float4*)&X[(size_t)(m0 + am) * 512 + k0 + ak];
        float4 a1 = *(const float4*)&X[(size_t)(m0 + am + 64) * 512 + k0 + ak];
        float4 bv = *(const float4*)&W[(size_t)(k0 + bk) * 1024 + n0 + bn];
        As[ak + 0][am] = a0.x; As[ak + 1][am] = a0.y;
        As[ak + 2][am] = a0.z; As[ak + 3][am] = a0.w;
        As[ak + 0][am + 64] = a1.x; As[ak + 1][am + 64] = a1.y;
        As[ak + 2][am + 64] = a1.z; As[ak + 3][am + 64] = a1.w;
        *(float4*)&Bs[bk][bn] = bv;
        __syncthreads();
        #pragma unroll
        for (int kk = 0; kk < 16; ++kk) {
            float4 x0 = *(const float4*)&As[kk][ty * 8];
            float4 x1 = *(const float4*)&As[kk][ty * 8 + 4];
            float4 y  = *(const float4*)&Bs[kk][tx * 4];
            float a[8] = {x0.x, x0.y, x0.z, x0.w, x1.x, x1.y, x1.z, x1.w};
            float bb[4] = {y.x, y.y, y.z, y.w};
            #pragma unroll
            for (int i = 0; i < 8; ++i)
                #pragma unroll
                for (int j = 0; j < 4; ++j)
                    acc[i][j] += a[i] * bb[j];
        }
    }
    #pragma unroll
    for (int i = 0; i < 8; ++i) {
        float4 r;
        r.x = acc[i][0]; r.y = acc[i][1]; r.z = acc[i][2]; r.w = acc[i][3];
        *(float4*)&out[(size_t)(m0 + ty * 8 + i) * 1024 + n0 + tx * 4] = r;
    }
}

// ---------------------------------------------------------------------------
// q, k, lambda projections.
// ---------------------------------------------------------------------------
__global__ __launch_bounds__(256) void qkl_kernel(const float* __restrict__ X,
    const float* __restrict__ Wq, const float* __restrict__ Wk,
    const float* __restrict__ Wd, const float* __restrict__ bd,
    float* __restrict__ q, float* __restrict__ k, float* __restrict__ lam)
{
    __shared__ float xs[8 * 512];
    const int tid = threadIdx.x;
    const size_t row0 = (size_t)blockIdx.x * 8;
    #pragma unroll
    for (int c = 0; c < 4; ++c) {
        int f = (c * 256 + tid) * 4;
        *(float4*)&xs[f] = *(const float4*)&X[row0 * 512 + f];
    }
    __syncthreads();
    for (int t = tid; t < 264; t += 256) {
        int r = t / 33, c = t - r * 33;
        const float* xr = &xs[r * 512];
        const float* Wp; int ldw;
        if (c < 16)      { Wp = Wq + c;        ldw = 16; }
        else if (c < 32) { Wp = Wk + (c - 16); ldw = 16; }
        else             { Wp = Wd;            ldw = 1;  }
        float s = 0.f;
        for (int kk = 0; kk < 512; ++kk) s += xr[kk] * Wp[(size_t)kk * ldw];
        if (c < 16)      q[(row0 + r) * 16 + c] = s;
        else if (c < 32) k[(row0 + r) * 16 + (c - 16)] = s;
        else             lam[row0 + r] = 1.f / (1.f + expf(-(s + bd[0])));
    }
}

// ---------------------------------------------------------------------------
// Fused recurrence: h_t = tanh(xw_t + h_{t-1}@Wh + F_t q_t + b), with the
// fast-weight scan (F update + read) folded into wave 3 (h-independent,
// computed BEFORE the poll -> hidden under the wait).
//
// 256 WGs = 64 col-slices x 4 batch-groups; 256 threads = 64 k-windows x
// 4 cols. Each thread polls ONLY its own 16-value window (one producer)
// directly from global (self-signaling +-4 offsets, sc0 sc1) -> wave-level
// skew tolerance, no LDS h staging, no pre-compute barrier. In-wave
// __shfl_xor butterfly reduces the 16 windows per wave; finisher sums 4
// wave-partials + pre from LDS, tanh, stores.
// ---------------------------------------------------------------------------
__global__ __launch_bounds__(256, 1) void rec_fused(
    const float* __restrict__ Wh, const float* __restrict__ qg,
    const float* __restrict__ kg, const float* __restrict__ vg,
    const float* __restrict__ lamg, const float* __restrict__ bias,
    float* __restrict__ out0, float* __restrict__ hfin,
    float* __restrict__ Ffin, float* __restrict__ hbuf)
{
    __shared__ float red2[2][256];     // [buf][wave*64 + col*4 + b]
    __shared__ float pre_lds[2][64];   // [buf][b*16 + col]
    __shared__ float F_lds[64][17];    // fast-weight state, pad 17

    const int tid = threadIdx.x;
    const int w = blockIdx.x;
    const int sl = w & 63, g = w >> 6;
    const int c0 = sl * 16;
    const int p  = tid >> 2;          // k-window index 0..63
    const int c4 = tid & 3;           // col quad
    const int wv = tid >> 6;          // wave id

    // Pre-loaded weights, all indices compile-time after unroll.
    float wr[64];
    #pragma unroll
    for (int i = 0; i < 16; ++i)
        #pragma unroll
        for (int j = 0; j < 4; ++j)
            wr[i * 4 + j] = Wh[(size_t)(16 * p + i) * 1024 + c0 + c4 * 4 + j];

    const int j64 = tid & 63;
    const int sb = j64 >> 4, scol = j64 & 15;   // scan/finisher (b, col)
    const int sbg = g * 4 + sb;
    const bool isScan = (tid >= 192);
    const bool isFin  = (tid < 64);
    float bias_r = 0.f;
    if (isScan) {
        bias_r = bias[c0 + scol];
        #pragma unroll
        for (int r = 0; r < 16; ++r) F_lds[j64][r] = 0.f;
    }

    for (int t = 0; t < Tc; ++t) {
        const int buf = t & 1;
        float* h_rd = hbuf + (t & 1) * (Bc * Hc) + g * 4096;
        float* h_wr = hbuf + ((t + 1) & 1) * (Bc * Hc) + g * 4096;
        const float off_r = ((t >> 1) & 1) ? 4.0f : 0.0f;
        const float off_w = (((t + 1) >> 1) & 1) ? 4.0f : 0.0f;

        // ---- wave3: advance fast-weight scan (h-independent) ----
        if (isScan) {
            const size_t row = (size_t)sbg * Tc + t;
            const float lamt = lamg[row];
            const float vt   = vg[row * Hc + c0 + scol];
            const float xwt  = out0[row * Hc + c0 + scol];
            const float* qp = qg + row * 16;
            const float* kp = kg + row * 16;
            float rd = 0.f;
            #pragma unroll
            for (int r4 = 0; r4 < 4; ++r4) {
                float4 q4 = *(const float4*)(qp + r4 * 4);
                float4 k4 = *(const float4*)(kp + r4 * 4);
                float f0 = F_lds[j64][r4 * 4 + 0];
                float f1 = F_lds[j64][r4 * 4 + 1];
                float f2 = F_lds[j64][r4 * 4 + 2];
                float f3 = F_lds[j64][r4 * 4 + 3];
                f0 = lamt * f0 + vt * k4.x; rd += f0 * q4.x;
                f1 = lamt * f1 + vt * k4.y; rd += f1 * q4.y;
                f2 = lamt * f2 + vt * k4.z; rd += f2 * q4.z;
                f3 = lamt * f3 + vt * k4.w; rd += f3 * q4.w;
                F_lds[j64][r4 * 4 + 0] = f0;
                F_lds[j64][r4 * 4 + 1] = f1;
                F_lds[j64][r4 * 4 + 2] = f2;
                F_lds[j64][r4 * 4 + 3] = f3;
            }
            pre_lds[buf][j64] = xwt + rd + bias_r;
            if (t == Tc - 1) {
                #pragma unroll
                for (int r = 0; r < 16; ++r)
                    Ffin[((size_t)sbg * Hc + c0 + scol) * 16 + r] = F_lds[j64][r];
            }
        }

        // ---- poll own window + partial matvec ----
        float acc[16];
        #pragma unroll
        for (int z = 0; z < 16; ++z) acc[z] = 0.f;
        if (t > 0) {
            const float lo = off_r - 1.5f, hi = off_r + 1.5f;
            const float* b0 = h_rd + 0 * 1024 + p * 16;
            const float* b1 = h_rd + 1 * 1024 + p * 16;
            const float* b2 = h_rd + 2 * 1024 + p * 16;
            const float* b3 = h_rd + 3 * 1024 + p * 16;
            float4 A0, A1, A2, A3, B0, B1, B2, B3;
            float4 C0, C1, C2, C3, D0, D1, D2, D3;
            while (1) {
                asm volatile(
                    "global_load_dwordx4 %0,  %16, off sc0 sc1\n\t"
                    "global_load_dwordx4 %1,  %16, off offset:16 sc0 sc1\n\t"
                    "global_load_dwordx4 %2,  %16, off offset:32 sc0 sc1\n\t"
                    "global_load_dwordx4 %3,  %16, off offset:48 sc0 sc1\n\t"
                    "global_load_dwordx4 %4,  %17, off sc0 sc1\n\t"
                    "global_load_dwordx4 %5,  %17, off offset:16 sc0 sc1\n\t"
                    "global_load_dwordx4 %6,  %17, off offset:32 sc0 sc1\n\t"
                    "global_load_dwordx4 %7,  %17, off offset:48 sc0 sc1\n\t"
                    "global_load_dwordx4 %8,  %18, off sc0 sc1\n\t"
                    "global_load_dwordx4 %9,  %18, off offset:16 sc0 sc1\n\t"
                    "global_load_dwordx4 %10, %18, off offset:32 sc0 sc1\n\t"
                    "global_load_dwordx4 %11, %18, off offset:48 sc0 sc1\n\t"
                    "global_load_dwordx4 %12, %19, off sc0 sc1\n\t"
                    "global_load_dwordx4 %13, %19, off offset:16 sc0 sc1\n\t"
                    "global_load_dwordx4 %14, %19, off offset:32 sc0 sc1\n\t"
                    "global_load_dwordx4 %15, %19, off offset:48 sc0 sc1\n\t"
                    "s_waitcnt vmcnt(0)"
                    : "=&v"(A0), "=&v"(A1), "=&v"(A2), "=&v"(A3),
                      "=&v"(B0), "=&v"(B1), "=&v"(B2), "=&v"(B3),
                      "=&v"(C0), "=&v"(C1), "=&v"(C2), "=&v"(C3),
                      "=&v"(D0), "=&v"(D1), "=&v"(D2), "=&v"(D3)
                    : "v"(b0), "v"(b1), "v"(b2), "v"(b3)
                    : "memory");
                #define CHK4(V) (V.x > lo && V.x < hi && V.y > lo && V.y < hi \
                              && V.z > lo && V.z < hi && V.w > lo && V.w < hi)
                bool ok = CHK4(A0) && CHK4(A1) && CHK4(A2) && CHK4(A3)
                       && CHK4(B0) && CHK4(B1) && CHK4(B2) && CHK4(B3)
                       && CHK4(C0) && CHK4(C1) && CHK4(C2) && CHK4(C3)
                       && CHK4(D0) && CHK4(D1) && CHK4(D2) && CHK4(D3);
                #undef CHK4
                if (ok) break;
            }
            float4 win[4][4] = {{A0, A1, A2, A3}, {B0, B1, B2, B3},
                                {C0, C1, C2, C3}, {D0, D1, D2, D3}};
            #pragma unroll
            for (int b = 0; b < 4; ++b)
                #pragma unroll
                for (int e = 0; e < 4; ++e) {
                    float4 hv = win[b][e];
                    hv.x -= off_r; hv.y -= off_r; hv.z -= off_r; hv.w -= off_r;
                    #pragma unroll
                    for (int j = 0; j < 4; ++j)
                        acc[j * 4 + b] += hv.x * wr[(e * 4 + 0) * 4 + j]
                                        + hv.y * wr[(e * 4 + 1) * 4 + j]
                                        + hv.z * wr[(e * 4 + 2) * 4 + j]
                                        + hv.w * wr[(e * 4 + 3) * 4 + j];
                }
        }

        // ---- in-wave butterfly over the 16 windows of this wave ----
        #pragma unroll
        for (int z = 0; z < 16; ++z) {
            float s = acc[z];
            s += __shfl_xor(s, 4);
            s += __shfl_xor(s, 8);
            s += __shfl_xor(s, 16);
            s += __shfl_xor(s, 32);
            acc[z] = s;
        }
        if ((tid & 63) < 4) {
            #pragma unroll
            for (int j = 0; j < 4; ++j) {
                float4 r4;
                r4.x = acc[j * 4 + 0]; r4.y = acc[j * 4 + 1];
                r4.z = acc[j * 4 + 2]; r4.w = acc[j * 4 + 3];
                *(float4*)&red2[buf][wv * 64 + ((tid & 3) * 4 + j) * 4] = r4;
            }
        }
        __syncthreads();

        // ---- finisher: combine, tanh, store ----
        if (isFin) {
            float tot = pre_lds[buf][tid];
            #pragma unroll
            for (int ww = 0; ww < 4; ++ww)
                tot += red2[buf][ww * 64 + scol * 4 + sb];
            float hv = tanhf(tot);
            float sv = hv + off_w;                 // self-signaling store first
            float* hp = h_wr + sb * 1024 + c0 + scol;
            asm volatile(
                "global_store_dword %0, %1, off sc0 sc1"
                :: "v"(hp), "v"(sv) : "memory");
            size_t oidx = ((size_t)sbg * Tc + t) * Hc + c0 + scol;
            out0[oidx] = hv;
            if (t == Tc - 1) hfin[(size_t)sbg * Hc + c0 + scol] = hv;
        }
    }
}

// ---------------------------------------------------------------------------
extern "C" void kernel_launch(void* const* d_in, const int* in_sizes, int n_in,
                              void* d_out, int out_size, void* d_ws, size_t ws_size,
                              hipStream_t stream)
{
    const float* x    = (const float*)d_in[0];
    const float* Wx   = (const float*)d_in[1];
    const float* Wh   = (const float*)d_in[2];
    const float* Wq   = (const float*)d_in[3];
    const float* Wk   = (const float*)d_in[4];
    const float* Wv   = (const float*)d_in[5];
    const float* Wd   = (const float*)d_in[6];
    const float* bias = (const float*)d_in[7];
    const float* bd   = (const float*)d_in[8];

    float* out0 = (float*)d_out;                    // (B,T,H): xw, then h
    float* hfin = out0 + (size_t)Bc * Tc * Hc;      // (B,H)
    float* Ffin = hfin + (size_t)Bc * Hc;           // (B,H,R)

    float* wsf  = (float*)d_ws;
    float* v    = wsf;                               // B*T*H
    float* q    = v + (size_t)Bc * Tc * Hc;          // B*T*R
    float* k    = q + (size_t)Bc * Tc * Rc;          // B*T*R
    float* lam  = k + (size_t)Bc * Tc * Rc;          // B*T
    float* hbuf = lam + (size_t)Bc * Tc;             // 2 * B*H ping-pong

    // 0x7F7F7F7F == 3.39e38f: invalid under both offsets -> poll-safe init.
    hipMemsetAsync(hbuf, 0x7F, 2 * (size_t)Bc * Hc * sizeof(float), stream);

    dim3 gg(256, 16);
    gemm_xw<<<gg, 256, 0, stream>>>(x, Wx, out0);   // xw -> out0
    gemm_xw<<<gg, 256, 0, stream>>>(x, Wv, v);      // v  -> ws
    qkl_kernel<<<4096, 256, 0, stream>>>(x, Wq, Wk, Wd, bd, q, k, lam);
    rec_fused<<<256, 256, 0, stream>>>(Wh, q, k, v, lam, bias,
                                       out0, hfin, Ffin, hbuf);
}

// Round 6
// 8838.202 us; speedup vs baseline: 1.2995x; 1.2995x over previous
//
#include <hip/hip_runtime.h>
#include <math.h>

#define Bc 16
#define Tc 2048
#define Dc 512
#define Hc 1024
#define Rc 16

// ---------------------------------------------------------------------------
// GEMM: out[M,1024] = X[M,512] @ W[512,1024], M = 32768.
// ---------------------------------------------------------------------------
__global__ __launch_bounds__(256) void gemm_xw(const float* __restrict__ X,
                                               const float* __restrict__ W,
                                               float* __restrict__ out)
{
    __shared__ float As[16][128];
    __shared__ float Bs[16][64];
    const int tid = threadIdx.x;
    const int m0 = blockIdx.x * 128;
    const int n0 = blockIdx.y * 64;
    const int tx = tid & 15, ty = tid >> 4;
    const int am = tid >> 2, ak = (tid & 3) * 4;
    const int bk = tid >> 4, bn = (tid & 15) * 4;
    float acc[8][4] = {};
    for (int k0 = 0; k0 < 512; k0 += 16) {
        if (k0) __syncthreads();
        float4 a0 = *(const float4*)&X[(size_t)(m0 + am) * 512 + k0 + ak];
        float4 a1 = *(const float4*)&X[(size_t)(m0 + am + 64) * 512 + k0 + ak];
        float4 bv = *(const float4*)&W[(size_t)(k0 + bk) * 1024 + n0 + bn];
        As[ak + 0][am] = a0.x; As[ak + 1][am] = a0.y;
        As[ak + 2][am] = a0.z; As[ak + 3][am] = a0.w;
        As[ak + 0][am + 64] = a1.x; As[ak + 1][am + 64] = a1.y;
        As[ak + 2][am + 64] = a1.z; As[ak + 3][am + 64] = a1.w;
        *(float4*)&Bs[bk][bn] = bv;
        __syncthreads();
        #pragma unroll
        for (int kk = 0; kk < 16; ++kk) {
            float4 x0 = *(const float4*)&As[kk][ty * 8];
            float4 x1 = *(const float4*)&As[kk][ty * 8 + 4];
            float4 y  = *(const float4*)&Bs[kk][tx * 4];
            float a[8] = {x0.x, x0.y, x0.z, x0.w, x1.x, x1.y, x1.z, x1.w};
            float bb[4] = {y.x, y.y, y.z, y.w};
            #pragma unroll
            for (int i = 0; i < 8; ++i)
                #pragma unroll
                for (int j = 0; j < 4; ++j)
                    acc[i][j] += a[i] * bb[j];
        }
    }
    #pragma unroll
    for (int i = 0; i < 8; ++i) {
        float4 r;
        r.x = acc[i][0]; r.y = acc[i][1]; r.z = acc[i][2]; r.w = acc[i][3];
        *(float4*)&out[(size_t)(m0 + ty * 8 + i) * 1024 + n0 + tx * 4] = r;
    }
}

// ---------------------------------------------------------------------------
// q, k, lambda projections.
// ---------------------------------------------------------------------------
__global__ __launch_bounds__(256) void qkl_kernel(const float* __restrict__ X,
    const float* __restrict__ Wq, const float* __restrict__ Wk,
    const float* __restrict__ Wd, const float* __restrict__ bd,
    float* __restrict__ q, float* __restrict__ k, float* __restrict__ lam)
{
    __shared__ float xs[8 * 512];
    const int tid = threadIdx.x;
    const size_t row0 = (size_t)blockIdx.x * 8;
    #pragma unroll
    for (int c = 0; c < 4; ++c) {
        int f = (c * 256 + tid) * 4;
        *(float4*)&xs[f] = *(const float4*)&X[row0 * 512 + f];
    }
    __syncthreads();
    for (int t = tid; t < 264; t += 256) {
        int r = t / 33, c = t - r * 33;
        const float* xr = &xs[r * 512];
        const float* Wp; int ldw;
        if (c < 16)      { Wp = Wq + c;        ldw = 16; }
        else if (c < 32) { Wp = Wk + (c - 16); ldw = 16; }
        else             { Wp = Wd;            ldw = 1;  }
        float s = 0.f;
        for (int kk = 0; kk < 512; ++kk) s += xr[kk] * Wp[(size_t)kk * ldw];
        if (c < 16)      q[(row0 + r) * 16 + c] = s;
        else if (c < 32) k[(row0 + r) * 16 + (c - 16)] = s;
        else             lam[row0 + r] = 1.f / (1.f + expf(-(s + bd[0])));
    }
}

// ---------------------------------------------------------------------------
// Fused recurrence: h_t = tanh(xw_t + h_{t-1}@Wh + F_t q_t + b).
// R6 = R4's proven exchange (contiguous poll, LDS h-staging, self-signaling
// +-4 data offsets, sc0 sc1) + 4x fewer LDS reads in the matvec:
//   threads = (kp 0..63: 16 k's) x (cg 0..3: 4 cols), each h float4 feeds
//   16 FMAs (4 cols x 4 batches). hs is chunk-padded (16 floats stored per
//   20-float slot) so the 16-distinct-address b128 reads are <=2-way.
//   Cross-kp reduce: in-wave __shfl_xor butterfly, then 4-deep LDS combine.
// Fast-weight scan fused on wave3 (h-independent, hidden under the poll)
// with one-step-ahead prefetch of its global inputs.
// ---------------------------------------------------------------------------
__global__ __launch_bounds__(256, 1) void rec_fused(
    const float* __restrict__ Wh, const float* __restrict__ qg,
    const float* __restrict__ kg, const float* __restrict__ vg,
    const float* __restrict__ lamg, const float* __restrict__ bias,
    float* __restrict__ out0, float* __restrict__ hfin,
    float* __restrict__ Ffin, float* __restrict__ hbuf)
{
    __shared__ float hs[4 * 1280];     // phys(b,k) = b*1280 + (k>>4)*20 + (k&15)
    __shared__ float red2[2][256];     // [buf][wv*64 + col*4 + b]
    __shared__ float pre_lds[2][64];   // [buf][b*16 + col]
    __shared__ float F_lds[64][17];    // fast-weight state, pad 17

    const int tid = threadIdx.x;
    const int w = blockIdx.x;
    const int sl = w & 63, g = w >> 6;
    const int c0 = sl * 16;
    const int kp = tid >> 2;          // k-part (16 k's)
    const int cg = tid & 3;           // col group (cols cg*4+j)
    const int wv = tid >> 6;

    // Weights: wr[i*4+j] = Wh[kp*16+i][c0+cg*4+j]; all indices static.
    float wr[64];
    #pragma unroll
    for (int i = 0; i < 16; ++i) {
        float4 w4 = *(const float4*)&Wh[(size_t)(kp * 16 + i) * 1024 + c0 + cg * 4];
        wr[i * 4 + 0] = w4.x; wr[i * 4 + 1] = w4.y;
        wr[i * 4 + 2] = w4.z; wr[i * 4 + 3] = w4.w;
    }

    const int j64 = tid & 63;
    const int sb = j64 >> 4, scol = j64 & 15;
    const int sbg = g * 4 + sb;
    const bool isScan = (tid >= 192);
    const bool isFin  = (tid < 64);
    float bias_r = 0.f;
    float4 pq[4], pk4[4];
    float plam = 0.f, pv = 0.f, pxw = 0.f;
    if (isScan) {
        bias_r = bias[c0 + scol];
        #pragma unroll
        for (int r = 0; r < 16; ++r) F_lds[j64][r] = 0.f;
        const size_t row = (size_t)sbg * Tc;            // t = 0 inputs
        plam = lamg[row];
        pv   = vg[row * Hc + c0 + scol];
        pxw  = out0[row * Hc + c0 + scol];
        const float* qp = qg + row * 16;
        const float* kpp = kg + row * 16;
        #pragma unroll
        for (int r4 = 0; r4 < 4; ++r4) {
            pq[r4]  = *(const float4*)(qp + r4 * 4);
            pk4[r4] = *(const float4*)(kpp + r4 * 4);
        }
    }

    for (int t = 0; t < Tc; ++t) {
        const int buf = t & 1;
        float* h_rd = hbuf + (t & 1) * (Bc * Hc) + g * 4096;
        float* h_wr = hbuf + ((t + 1) & 1) * (Bc * Hc) + g * 4096;
        const float off_r = ((t >> 1) & 1) ? 4.0f : 0.0f;
        const float off_w = (((t + 1) >> 1) & 1) ? 4.0f : 0.0f;

        // ---- wave3: fast-weight scan from prefetched inputs ----
        if (isScan) {
            float rd = 0.f;
            #pragma unroll
            for (int r4 = 0; r4 < 4; ++r4) {
                float f0 = F_lds[j64][r4 * 4 + 0];
                float f1 = F_lds[j64][r4 * 4 + 1];
                float f2 = F_lds[j64][r4 * 4 + 2];
                float f3 = F_lds[j64][r4 * 4 + 3];
                f0 = plam * f0 + pv * pk4[r4].x; rd += f0 * pq[r4].x;
                f1 = plam * f1 + pv * pk4[r4].y; rd += f1 * pq[r4].y;
                f2 = plam * f2 + pv * pk4[r4].z; rd += f2 * pq[r4].z;
                f3 = plam * f3 + pv * pk4[r4].w; rd += f3 * pq[r4].w;
                F_lds[j64][r4 * 4 + 0] = f0;
                F_lds[j64][r4 * 4 + 1] = f1;
                F_lds[j64][r4 * 4 + 2] = f2;
                F_lds[j64][r4 * 4 + 3] = f3;
            }
            pre_lds[buf][j64] = pxw + rd + bias_r;
            if (t == Tc - 1) {
                #pragma unroll
                for (int r = 0; r < 16; ++r)
                    Ffin[((size_t)sbg * Hc + c0 + scol) * 16 + r] = F_lds[j64][r];
            } else {
                const size_t row = (size_t)sbg * Tc + (t + 1);
                plam = lamg[row];
                pv   = vg[row * Hc + c0 + scol];
                pxw  = out0[row * Hc + c0 + scol];
                const float* qp = qg + row * 16;
                const float* kpp = kg + row * 16;
                #pragma unroll
                for (int r4 = 0; r4 < 4; ++r4) {
                    pq[r4]  = *(const float4*)(qp + r4 * 4);
                    pk4[r4] = *(const float4*)(kpp + r4 * 4);
                }
            }
        }

        // ---- poll own contiguous window (R4 scheme), stage into hs ----
        {
            const int chunk = tid >> 2, coff = (tid & 3) * 4;
            float* base = &hs[chunk * 20 + coff];
            if (t > 0) {
                const float lo = off_r - 1.5f, hi = off_r + 1.5f;
                const float* p0 = h_rd + tid * 4;
                const float* p1 = p0 + 1024;
                const float* p2 = p0 + 2048;
                const float* p3 = p0 + 3072;
                float4 r0, r1, r2, r3;
                while (1) {
                    asm volatile(
                        "global_load_dwordx4 %0, %4, off sc0 sc1\n\t"
                        "global_load_dwordx4 %1, %5, off sc0 sc1\n\t"
                        "global_load_dwordx4 %2, %6, off sc0 sc1\n\t"
                        "global_load_dwordx4 %3, %7, off sc0 sc1\n\t"
                        "s_waitcnt vmcnt(0)"
                        : "=&v"(r0), "=&v"(r1), "=&v"(r2), "=&v"(r3)
                        : "v"(p0), "v"(p1), "v"(p2), "v"(p3)
                        : "memory");
                    bool ok = r0.x > lo && r0.x < hi && r0.y > lo && r0.y < hi
                           && r0.z > lo && r0.z < hi && r0.w > lo && r0.w < hi
                           && r1.x > lo && r1.x < hi && r1.y > lo && r1.y < hi
                           && r1.z > lo && r1.z < hi && r1.w > lo && r1.w < hi
                           && r2.x > lo && r2.x < hi && r2.y > lo && r2.y < hi
                           && r2.z > lo && r2.z < hi && r2.w > lo && r2.w < hi
                           && r3.x > lo && r3.x < hi && r3.y > lo && r3.y < hi
                           && r3.z > lo && r3.z < hi && r3.w > lo && r3.w < hi;
                    if (ok) break;
                }
                r0.x -= off_r; r0.y -= off_r; r0.z -= off_r; r0.w -= off_r;
                r1.x -= off_r; r1.y -= off_r; r1.z -= off_r; r1.w -= off_r;
                r2.x -= off_r; r2.y -= off_r; r2.z -= off_r; r2.w -= off_r;
                r3.x -= off_r; r3.y -= off_r; r3.z -= off_r; r3.w -= off_r;
                *(float4*)(base + 0 * 1280) = r0;
                *(float4*)(base + 1 * 1280) = r1;
                *(float4*)(base + 2 * 1280) = r2;
                *(float4*)(base + 3 * 1280) = r3;
            } else {
                float4 z = {0.f, 0.f, 0.f, 0.f};
                *(float4*)(base + 0 * 1280) = z;
                *(float4*)(base + 1 * 1280) = z;
                *(float4*)(base + 2 * 1280) = z;
                *(float4*)(base + 3 * 1280) = z;
            }
        }
        __syncthreads();                       // hs ready

        // ---- matvec: 16 b128 LDS reads, 256 FMAs per thread ----
        float acc[16];
        #pragma unroll
        for (int z = 0; z < 16; ++z) acc[z] = 0.f;
        #pragma unroll
        for (int b = 0; b < 4; ++b) {
            const float* hb = &hs[b * 1280 + kp * 20];
            #pragma unroll
            for (int e = 0; e < 4; ++e) {
                float4 h4 = *(const float4*)(hb + e * 4);
                #pragma unroll
                for (int j = 0; j < 4; ++j)
                    acc[j * 4 + b] += h4.x * wr[(e * 4 + 0) * 4 + j]
                                    + h4.y * wr[(e * 4 + 1) * 4 + j]
                                    + h4.z * wr[(e * 4 + 2) * 4 + j]
                                    + h4.w * wr[(e * 4 + 3) * 4 + j];
            }
        }

        // ---- in-wave butterfly over the 16 k-parts of this wave ----
        #pragma unroll
        for (int z = 0; z < 16; ++z) {
            float s = acc[z];
            s += __shfl_xor(s, 4);
            s += __shfl_xor(s, 8);
            s += __shfl_xor(s, 16);
            s += __shfl_xor(s, 32);
            acc[z] = s;
        }
        if (j64 < 4) {                          // kpl==0 lanes; j64 == cg
            #pragma unroll
            for (int j = 0; j < 4; ++j) {
                float4 r4;
                r4.x = acc[j * 4 + 0]; r4.y = acc[j * 4 + 1];
                r4.z = acc[j * 4 + 2]; r4.w = acc[j * 4 + 3];
                *(float4*)&red2[buf][wv * 64 + (j64 * 4 + j) * 4] = r4;
            }
        }
        __syncthreads();                       // red2 + pre_lds ready

        // ---- finisher: combine 4 wave-partials, tanh, store ----
        if (isFin) {
            const int fb = tid >> 4, fcol = tid & 15;
            float tot = pre_lds[buf][tid];
            #pragma unroll
            for (int ww = 0; ww < 4; ++ww)
                tot += red2[buf][ww * 64 + fcol * 4 + fb];
            float hv = tanhf(tot);
            float sv = hv + off_w;             // self-signaling store first
            float* hp = h_wr + fb * 1024 + c0 + fcol;
            asm volatile(
                "global_store_dword %0, %1, off sc0 sc1"
                :: "v"(hp), "v"(sv) : "memory");
            size_t oidx = ((size_t)(g * 4 + fb) * Tc + t) * Hc + c0 + fcol;
            out0[oidx] = hv;
            if (t == Tc - 1) hfin[(size_t)(g * 4 + fb) * Hc + c0 + fcol] = hv;
        }
    }
}

// ---------------------------------------------------------------------------
extern "C" void kernel_launch(void* const* d_in, const int* in_sizes, int n_in,
                              void* d_out, int out_size, void* d_ws, size_t ws_size,
                              hipStream_t stream)
{
    const float* x    = (const float*)d_in[0];
    const float* Wx   = (const float*)d_in[1];
    const float* Wh   = (const float*)d_in[2];
    const float* Wq   = (const float*)d_in[3];
    const float* Wk   = (const float*)d_in[4];
    const float* Wv   = (const float*)d_in[5];
    const float* Wd   = (const float*)d_in[6];
    const float* bias = (const float*)d_in[7];
    const float* bd   = (const float*)d_in[8];

    float* out0 = (float*)d_out;                    // (B,T,H): xw, then h
    float* hfin = out0 + (size_t)Bc * Tc * Hc;      // (B,H)
    float* Ffin = hfin + (size_t)Bc * Hc;           // (B,H,R)

    float* wsf  = (float*)d_ws;
    float* v    = wsf;                               // B*T*H
    float* q    = v + (size_t)Bc * Tc * Hc;          // B*T*R
    float* k    = q + (size_t)Bc * Tc * Rc;          // B*T*R
    float* lam  = k + (size_t)Bc * Tc * Rc;          // B*T
    float* hbuf = lam + (size_t)Bc * Tc;             // 2 * B*H ping-pong

    // 0x7F7F7F7F == 3.39e38f: invalid under both offsets -> poll-safe init.
    hipMemsetAsync(hbuf, 0x7F, 2 * (size_t)Bc * Hc * sizeof(float), stream);

    dim3 gg(256, 16);
    gemm_xw<<<gg, 256, 0, stream>>>(x, Wx, out0);   // xw -> out0
    gemm_xw<<<gg, 256, 0, stream>>>(x, Wv, v);      // v  -> ws
    qkl_kernel<<<4096, 256, 0, stream>>>(x, Wq, Wk, Wd, bd, q, k, lam);
    rec_fused<<<256, 256, 0, stream>>>(Wh, q, k, v, lam, bias,
                                       out0, hfin, Ffin, hbuf);
}